// Round 12
// baseline (61.367 us; speedup 1.0000x reference)
//
#include <hip/hip_runtime.h>
#include <math.h>

#define NB_TOTAL 65536
#define OUTS 773            // 2 + 514 + 257

typedef float f32x4 __attribute__((ext_vector_type(4)));
typedef float f32x2 __attribute__((ext_vector_type(2)));

// Output row layout (f32):
//  [0..1] x31 | [2+i] G flat i=2j+comp (512 vals) | [514,515] G_o
//  [516+m] h_s | [772] h_o
//
// prm row layout (16 f32):
//  [0]A0 [1]tvs [2]tvc [3]A1 | [4]tc [5]ts [6]x31_0 [7]x31_1
//  [8]Go0 [9]Go1 [10]ho [11]- | [12]C [13]u [14]w [15]pp
//  G0(j) = A0 - tvs*ox + tvc*oy ; G1(j) = A1 + tc*ox + ts*oy
//  h(m)  = C + u*ox + w*oy + pp*q ; q = ox^2+oy^2-R^2
//
// R12 schedule (within-wave interleave; every wave stores — R11 lesson):
//  block = 128 rows = 2 groups of 64; 4 waves; PH = wv (compile-time;
//  ROLE = PH&1, HALF = PH>>1).
//  A1(g0) | sync | A2(g0)->prm0 | sync |
//  { b_row(g0,t) x16  interleaved with  A1_iter(g1) x8 } | sync |
//  A2(g1)->prm1 | sync | b_row(g1,t) x16
//  -> A(g1) hides under B(g0) store drain.
// R7 lesson: only 16B-ALIGNED dwordx4 stores. R9 lesson: one row in flight.

__device__ __forceinline__ int iclamp(int v, int lo, int hi) {
    return v < lo ? lo : (v > hi ? hi : v);
}

struct Feats {
    float Ax[3], Ay[3], Bx[3], By[3];
    float Cx[4], Cy[4], Cq[4];
    float o0x, o0y, e255x, e255y;
    float Tx[3], Ty[3], Tq[3];
};

template<int PH>
__device__ __forceinline__ void load_feats(int l,
    const float* __restrict__ obstacles, Feats& f)
{
    constexpr int aStart = (PH == 0) ? 1 : (PH == 3 ? -1 : 0);
    constexpr int nA = (PH == 0 || PH == 2) ? 2 : 3;
    #pragma unroll
    for (int c = 0; c < nA; ++c) {
        const int j = iclamp(2 * l + aStart + c, 0, 255);
        const float* o = obstacles + (size_t)j * 3;
        f.Ax[c] = o[0]; f.Ay[c] = o[1];
    }
    #pragma unroll
    for (int c = 0; c < nA; ++c) {
        const int j = iclamp(2 * l + 128 + aStart + c, 0, 255);
        const float* o = obstacles + (size_t)j * 3;
        f.Bx[c] = o[0]; f.By[c] = o[1];
    }
    #pragma unroll
    for (int c = 0; c < 4; ++c) {
        const int j = iclamp(4 * l - PH + c, 0, 255);
        const float* o = obstacles + (size_t)j * 3;
        const float a = o[0], b = o[1], r = o[2] + 0.6f;  // R = 0.5+rad+0.1
        f.Cx[c] = a; f.Cy[c] = b; f.Cq[c] = fmaf(a, a, b * b) - r * r;
    }
    f.o0x = 0.f; f.o0y = 0.f; f.e255x = 0.f; f.e255y = 0.f;
    if (PH == 0 || PH == 1) { f.o0x = obstacles[0]; f.o0y = obstacles[1]; }
    if (PH == 3) { f.e255x = obstacles[255*3]; f.e255y = obstacles[255*3+1]; }
    if (PH >= 1) {
        #pragma unroll
        for (int c = 0; c < 3; ++c) {
            const float* o = obstacles + (size_t)(253 + c) * 3;
            const float a = o[0], b = o[1], r = o[2] + 0.6f;
            f.Tx[c] = a; f.Ty[c] = b; f.Tq[c] = fmaf(a, a, b * b) - r * r;
        }
    }
}

template<int PH>
__device__ __forceinline__ void b_row(
    int groupRow0, int l, const float (&prmg)[64][16], const Feats& f,
    float* __restrict__ out, int t)
{
    const int rloc = 4 * t + PH;
    const int row  = groupRow0 + rloc;

    const f32x4 c0 = *(const f32x4*)&prmg[rloc][0];
    const f32x4 c1 = *(const f32x4*)&prmg[rloc][4];
    const f32x4 c2 = *(const f32x4*)&prmg[rloc][8];
    const f32x4 c3 = *(const f32x4*)&prmg[rloc][12];
    const float A0 = c0.x, tvs = c0.y, tvc = c0.z, A1 = c0.w;
    const float tc = c1.x, ts  = c1.y, x31_0 = c1.z, x31_1 = c1.w;
    const float Go0 = c2.x, Go1 = c2.y, ho = c2.z;
    const float C = c3.x, u = c3.y, w = c3.z, pp = c3.w;

    auto G0 = [&](float X, float Y) { return fmaf(Y, tvc, fmaf(-X, tvs, A0)); };
    auto G1 = [&](float X, float Y) { return fmaf(Y, ts,  fmaf( X, tc,  A1)); };
    auto H  = [&](float X, float Y, float Q) {
        return fmaf(pp, Q, fmaf(w, Y, fmaf(u, X, C)));
    };

    const unsigned base = (unsigned)row * 773u;
    float* a0p = out + (base - (unsigned)PH);        // 16B-aligned

    // chunk A: k = l+1
    f32x4 vA;
    if (PH == 0 || PH == 2)
        vA = (f32x4){G0(f.Ax[0],f.Ay[0]), G1(f.Ax[0],f.Ay[0]),
                     G0(f.Ax[1],f.Ay[1]), G1(f.Ax[1],f.Ay[1])};
    else
        vA = (f32x4){G1(f.Ax[0],f.Ay[0]), G0(f.Ax[1],f.Ay[1]),
                     G1(f.Ax[1],f.Ay[1]), G0(f.Ax[2],f.Ay[2])};
    if (PH == 3 && l == 0) vA.x = x31_1;             // f=1
    *(f32x4*)(a0p + 4 * (l + 1)) = vA;

    // chunk B: k = l+65
    f32x4 vB;
    if (PH == 0 || PH == 2)
        vB = (f32x4){G0(f.Bx[0],f.By[0]), G1(f.Bx[0],f.By[0]),
                     G0(f.Bx[1],f.By[1]), G1(f.Bx[1],f.By[1])};
    else
        vB = (f32x4){G1(f.Bx[0],f.By[0]), G0(f.Bx[1],f.By[1]),
                     G1(f.Bx[1],f.By[1]), G0(f.Bx[2],f.By[2])};
    if (l == 63) {                                   // i>=512 -> Go
        if (PH == 0) { vB.z = Go0; vB.w = Go1; }
        if (PH == 1) { vB.w = Go0; }
    }
    *(f32x4*)(a0p + 4 * (l + 65)) = vB;

    // chunk C: k = l+129
    f32x4 vC = (f32x4){H(f.Cx[0],f.Cy[0],f.Cq[0]), H(f.Cx[1],f.Cy[1],f.Cq[1]),
                       H(f.Cx[2],f.Cy[2],f.Cq[2]), H(f.Cx[3],f.Cy[3],f.Cq[3])};
    if (l == 0) {                                    // m<0 -> G511/Go
        if (PH == 1) { vC.x = Go1; }
        if (PH == 2) { vC.x = Go0; vC.y = Go1; }
        if (PH == 3) { vC.x = G1(f.e255x, f.e255y); vC.y = Go0; vC.z = Go1; }
    }
    *(f32x4*)(a0p + 4 * (l + 129)) = vC;

    // head chunk k=0 (lane 0)
    if (l == 0) {
        if (PH == 0) {
            *(f32x4*)a0p = (f32x4){x31_0, x31_1, G0(f.o0x,f.o0y), G1(f.o0x,f.o0y)};
        } else if (PH == 1) {
            a0p[1] = x31_0;
            *(f32x2*)(a0p + 2) = (f32x2){x31_1, G0(f.o0x,f.o0y)};
        } else if (PH == 2) {
            *(f32x2*)(a0p + 2) = (f32x2){x31_0, x31_1};
        } else {
            a0p[3] = x31_0;
        }
    }
    // tail chunk k=193 (lane 1)
    else if (l == 1) {
        float* tp = a0p + 772;                       // 16B-aligned
        if (PH == 0) {
            tp[0] = ho;
        } else if (PH == 1) {
            *(f32x2*)tp = (f32x2){H(f.Tx[2],f.Ty[2],f.Tq[2]), ho};
        } else if (PH == 2) {
            *(f32x2*)tp = (f32x2){H(f.Tx[1],f.Ty[1],f.Tq[1]),
                                  H(f.Tx[2],f.Ty[2],f.Tq[2])};
            tp[2] = ho;
        } else {
            *(f32x4*)tp = (f32x4){H(f.Tx[0],f.Ty[0],f.Tq[0]),
                                  H(f.Tx[1],f.Ty[1],f.Tq[1]),
                                  H(f.Tx[2],f.Ty[2],f.Tq[2]), ho};
        }
    }
}

__device__ __forceinline__ void load_x(const float* __restrict__ x, int row,
                                       float (&xr)[8])
{
    const float4 xa = *(const float4*)(x + (size_t)row * 8);
    const float4 xb = *(const float4*)(x + (size_t)row * 8 + 4);
    xr[0]=xa.x; xr[1]=xa.y; xr[2]=xa.z; xr[3]=xa.w;
    xr[4]=xb.x; xr[5]=xb.y; xr[6]=xb.z; xr[7]=xb.w;
}

template<int HALF>
__device__ __forceinline__ void A1_iter(
    const float (&xr)[8], float (&acc)[32], int it,
    const float* __restrict__ W1, const float* __restrict__ b1,
    const float* __restrict__ Wh)
{
    const int i0 = HALF * 64 + it * 8;
    float hh[8];
    #pragma unroll
    for (int u = 0; u < 8; ++u) {
        float a = b1[i0 + u];
        #pragma unroll
        for (int k = 0; k < 8; ++k)
            a = fmaf(xr[k], W1[k * 128 + i0 + u], a);
        hh[u] = fmaxf(a, 0.0f);
    }
    #pragma unroll
    for (int u = 0; u < 8; ++u) {
        #pragma unroll
        for (int k = 0; k < 32; ++k)
            acc[k] = fmaf(hh[u], Wh[(i0 + u) * 32 + k], acc[k]);
    }
}

template<int ROLE>
__device__ __forceinline__ void A2(
    int l, const float (&xr)[8], float (&acc)[32],
    const float (&pacc)[2][64][33],
    const float* __restrict__ input_mean, const float* __restrict__ input_std,
    const float* __restrict__ W31, const float* __restrict__ b31,
    const float* __restrict__ W32, const float* __restrict__ b32,
    float (&prmg)[64][16])
{
    #pragma unroll
    for (int k = 0; k < 32; ++k) acc[k] += pacc[ROLE][l][k];

    const float* Wo = ROLE ? W32 : W31;
    const float* bo = ROLE ? b32 : b31;
    float o0 = bo[0], o1 = bo[1];
    #pragma unroll
    for (int k = 0; k < 32; ++k) {
        float a = fmaxf(acc[k], 0.0f);
        o0 = fmaf(a, Wo[k * 2 + 0], o0);
        o1 = fmaf(a, Wo[k * 2 + 1], o1);
    }

    float x0v[8];
    #pragma unroll
    for (int k = 0; k < 8; ++k)
        x0v[k] = fmaf(xr[k], input_std[k], input_mean[k]);
    const float px = x0v[0], py = x0v[1], th = x0v[2], v = x0v[3];
    const float opx = x0v[4], opy = x0v[5], oth = x0v[6], ov = x0v[7];

    float st, ct, sto, cto;
    sincosf(th,  &st,  &ct);
    sincosf(oth, &sto, &cto);

    const float tvs = 2.0f * v * st;
    const float tvc = 2.0f * v * ct;
    const float tc  = 2.0f * ct;
    const float ts  = 2.0f * st;
    const float hc  = 2.0f * v * v;

    const float dxo = px - opx, dyo = py - opy;

    if (ROLE == 0) {
        const float A0  = px * tvs - py * tvc;
        const float A1  = -(px * tc + py * ts);
        const float Go0 = dxo * tvs - dyo * tvc;
        const float Go1 = -(dxo * tc + dyo * ts);
        *(f32x4*)&prmg[l][0] = (f32x4){A0, tvs, tvc, A1};
        *(f32x4*)&prmg[l][4] = (f32x4){tc, ts, o0, o1};
        *(f32x2*)&prmg[l][8] = (f32x2){Go0, Go1};
    } else {
        const float p0 = 4.0f / (1.0f + __expf(-o0));
        const float p1 = 4.0f / (1.0f + __expf(-o1));
        const float ps = p0 + p1;
        const float pp = p0 * p1;
        const float B0 = px * tvc + py * tvs;
        const float C  = hc + ps * B0 + pp * (px * px + py * py);
        const float u  = -(ps * tvc) - 2.0f * pp * px;
        const float w  = -(ps * tvs) - 2.0f * pp * py;
        const float ob  = dxo * dxo + dyo * dyo - 1.21f;     // Ro^2
        const float rvx = v * ct - ov * cto;
        const float rvy = v * st - ov * sto;
        const float obd = 2.0f * (dxo * rvx + dyo * rvy);
        const float cth_sum = ct * cto - st * sto;            // cos(th+oth)
        const float oLf2b = 2.0f * (v * v + ov * ov - 2.0f * v * ov * cth_sum);
        const float ho = oLf2b + ps * obd + pp * ob;
        *(f32x2*)&prmg[l][10]  = (f32x2){ho, 0.0f};
        *(f32x4*)&prmg[l][12]  = (f32x4){C, u, w, pp};
    }
}

template<int PH>
__device__ __forceinline__ void flow(
    int blockRow0, int l,
    float (&pacc)[2][64][33], float (&prm)[2][64][16],
    const float* __restrict__ x,
    const float* __restrict__ obstacles,
    const float* __restrict__ input_mean, const float* __restrict__ input_std,
    const float* __restrict__ W1,  const float* __restrict__ b1,
    const float* __restrict__ W21, const float* __restrict__ b21,
    const float* __restrict__ W22, const float* __restrict__ b22,
    const float* __restrict__ W31, const float* __restrict__ b31,
    const float* __restrict__ W32, const float* __restrict__ b32,
    float* __restrict__ out)
{
    constexpr int ROLE = PH & 1;
    constexpr int HALF = PH >> 1;
    const float* Wh = ROLE ? W22 : W21;
    const float* bh = ROLE ? b22 : b21;

    Feats f;
    load_feats<PH>(l, obstacles, f);

    // ---- stage 1: A1(g0) ---------------------------------------------------
    float xr0[8];
    load_x(x, blockRow0 + l, xr0);
    float acc[32];
    #pragma unroll
    for (int k = 0; k < 32; ++k) acc[k] = HALF ? 0.0f : bh[k];
    #pragma unroll 1
    for (int it = 0; it < 8; ++it)
        A1_iter<HALF>(xr0, acc, it, W1, b1, Wh);
    if (HALF == 0) {
        #pragma unroll
        for (int k = 0; k < 32; ++k) pacc[ROLE][l][k] = acc[k];
    }
    __syncthreads();                                 // 1: pacc(g0) ready

    if (HALF == 1)
        A2<ROLE>(l, xr0, acc, pacc, input_mean, input_std,
                 W31, b31, W32, b32, prm[0]);
    __syncthreads();                                 // 2: prm0 ready

    // ---- stage 2: B(g0) interleaved with A1(g1) ----------------------------
    float xr1[8];
    load_x(x, blockRow0 + 64 + l, xr1);
    #pragma unroll
    for (int k = 0; k < 32; ++k) acc[k] = HALF ? 0.0f : bh[k];
    #pragma unroll 1
    for (int t = 0; t < 16; ++t) {
        b_row<PH>(blockRow0, l, prm[0], f, out, t);
        if ((t & 1) == 0)
            A1_iter<HALF>(xr1, acc, t >> 1, W1, b1, Wh);
    }
    if (HALF == 0) {
        #pragma unroll
        for (int k = 0; k < 32; ++k) pacc[ROLE][l][k] = acc[k];
    }
    __syncthreads();                                 // 3: pacc(g1) ready

    if (HALF == 1)
        A2<ROLE>(l, xr1, acc, pacc, input_mean, input_std,
                 W31, b31, W32, b32, prm[1]);
    __syncthreads();                                 // 4: prm1 ready

    // ---- stage 3: B(g1) ----------------------------------------------------
    #pragma unroll 1
    for (int t = 0; t < 16; ++t)
        b_row<PH>(blockRow0 + 64, l, prm[1], f, out, t);
}

__global__ __launch_bounds__(256, 2) void fused6(
    const float* __restrict__ x,
    const float* __restrict__ obstacles,
    const float* __restrict__ input_mean, const float* __restrict__ input_std,
    const float* __restrict__ W1,  const float* __restrict__ b1,
    const float* __restrict__ W21, const float* __restrict__ b21,
    const float* __restrict__ W22, const float* __restrict__ b22,
    const float* __restrict__ W31, const float* __restrict__ b31,
    const float* __restrict__ W32, const float* __restrict__ b32,
    float* __restrict__ out)
{
    __shared__ float pacc[2][64][33];   // partial acc exchange (+1 pad)
    __shared__ float prm[2][64][16];    // per-group coefficients

    const int tid = threadIdx.x;
    const int l   = tid & 63;
    const int wv  = __builtin_amdgcn_readfirstlane(tid >> 6);   // 0..3
    const int blockRow0 = blockIdx.x * 128;

    if      (wv == 0) flow<0>(blockRow0, l, pacc, prm, x, obstacles,
                              input_mean, input_std, W1, b1, W21, b21,
                              W22, b22, W31, b31, W32, b32, out);
    else if (wv == 1) flow<1>(blockRow0, l, pacc, prm, x, obstacles,
                              input_mean, input_std, W1, b1, W21, b21,
                              W22, b22, W31, b31, W32, b32, out);
    else if (wv == 2) flow<2>(blockRow0, l, pacc, prm, x, obstacles,
                              input_mean, input_std, W1, b1, W21, b21,
                              W22, b22, W31, b31, W32, b32, out);
    else              flow<3>(blockRow0, l, pacc, prm, x, obstacles,
                              input_mean, input_std, W1, b1, W21, b21,
                              W22, b22, W31, b31, W32, b32, out);
}

extern "C" void kernel_launch(void* const* d_in, const int* in_sizes, int n_in,
                              void* d_out, int out_size, void* d_ws, size_t ws_size,
                              hipStream_t stream) {
    const float* x          = (const float*)d_in[0];
    const float* obstacles  = (const float*)d_in[1];
    const float* input_mean = (const float*)d_in[2];
    const float* input_std  = (const float*)d_in[3];
    const float* W1  = (const float*)d_in[4];
    const float* b1  = (const float*)d_in[5];
    const float* W21 = (const float*)d_in[6];
    const float* b21 = (const float*)d_in[7];
    const float* W22 = (const float*)d_in[8];
    const float* b22 = (const float*)d_in[9];
    const float* W31 = (const float*)d_in[10];
    const float* b31 = (const float*)d_in[11];
    const float* W32 = (const float*)d_in[12];
    const float* b32 = (const float*)d_in[13];

    float* out = (float*)d_out;

    // 512 blocks x 256 threads, 128 rows/block (2 groups of 64)
    fused6<<<dim3(NB_TOTAL / 128), dim3(256), 0, stream>>>(
        x, obstacles, input_mean, input_std,
        W1, b1, W21, b21, W22, b22, W31, b31, W32, b32, out);
}

// Round 13
// 53.048 us; speedup vs baseline: 1.1568x; 1.1568x over previous
//
#include <hip/hip_runtime.h>
#include <math.h>

#define NB_TOTAL 65536
#define OUTS 773            // 2 + 514 + 257

typedef float f32x4 __attribute__((ext_vector_type(4)));
typedef float f32x2 __attribute__((ext_vector_type(2)));

// Output row layout (f32):
//  [0..1] x31 | [2+i] G flat i=2j+comp (512 vals) | [514,515] G_o
//  [516+m] h_s | [772] h_o
//
// prm row layout (16 f32):
//  [0]A0 [1]tvs [2]tvc [3]A1 | [4]tc [5]ts [6]x31_0 [7]x31_1
//  [8]Go0 [9]Go1 [10]ho [11]- | [12]C [13]u [14]w [15]pp
//  G0(j) = A0 - tvs*ox + tvc*oy ; G1(j) = A1 + tc*ox + ts*oy
//  h(m)  = C + u*ox + w*oy + pp*q ; q = ox^2+oy^2-R^2
//
// R13 = R10 schedule (1024 blocks x 256 thr, 64 rows, phase-per-wave,
// 16 store-waves/CU — the proven-best shape) + two latency fixes:
//  (a) obstacle feature loads hoisted BEFORE phase A (hide under A VALU);
//  (b) prm coefficient prefetch in B (depth-2 software pipeline breaks the
//      per-row ds_read -> VALU -> store serial chain).
// R7 lesson: only 16B-ALIGNED dwordx4 stores. R9 lesson: one row's chunk
// values in flight. R11/R12 lesson: never reduce store-issuing waves/CU.

__device__ __forceinline__ int iclamp(int v, int lo, int hi) {
    return v < lo ? lo : (v > hi ? hi : v);
}

struct Feats {
    float Ax[3], Ay[3], Bx[3], By[3];
    float Cx[4], Cy[4], Cq[4];
    float o0x, o0y, e255x, e255y;
    float Tx[3], Ty[3], Tq[3];
};

template<int PH>
__device__ __forceinline__ void load_feats(int l,
    const float* __restrict__ obstacles, Feats& f)
{
    constexpr int aStart = (PH == 0) ? 1 : (PH == 3 ? -1 : 0);
    constexpr int nA = (PH == 0 || PH == 2) ? 2 : 3;
    #pragma unroll
    for (int c = 0; c < nA; ++c) {
        const int j = iclamp(2 * l + aStart + c, 0, 255);
        const float* o = obstacles + (size_t)j * 3;
        f.Ax[c] = o[0]; f.Ay[c] = o[1];
    }
    #pragma unroll
    for (int c = 0; c < nA; ++c) {
        const int j = iclamp(2 * l + 128 + aStart + c, 0, 255);
        const float* o = obstacles + (size_t)j * 3;
        f.Bx[c] = o[0]; f.By[c] = o[1];
    }
    #pragma unroll
    for (int c = 0; c < 4; ++c) {
        const int j = iclamp(4 * l - PH + c, 0, 255);
        const float* o = obstacles + (size_t)j * 3;
        const float a = o[0], b = o[1], r = o[2] + 0.6f;  // R = 0.5+rad+0.1
        f.Cx[c] = a; f.Cy[c] = b; f.Cq[c] = fmaf(a, a, b * b) - r * r;
    }
    f.o0x = 0.f; f.o0y = 0.f; f.e255x = 0.f; f.e255y = 0.f;
    if (PH == 0 || PH == 1) { f.o0x = obstacles[0]; f.o0y = obstacles[1]; }
    if (PH == 3) { f.e255x = obstacles[255*3]; f.e255y = obstacles[255*3+1]; }
    if (PH >= 1) {
        #pragma unroll
        for (int c = 0; c < 3; ++c) {
            const float* o = obstacles + (size_t)(253 + c) * 3;
            const float a = o[0], b = o[1], r = o[2] + 0.6f;
            f.Tx[c] = a; f.Ty[c] = b; f.Tq[c] = fmaf(a, a, b * b) - r * r;
        }
    }
}

// One row of phase B. Coefficients passed in registers (prefetched caller-side).
template<int PH>
__device__ __forceinline__ void b_row(
    int row, int l, f32x4 c0, f32x4 c1, f32x4 c2, f32x4 c3,
    const Feats& f, float* __restrict__ out)
{
    const float A0 = c0.x, tvs = c0.y, tvc = c0.z, A1 = c0.w;
    const float tc = c1.x, ts  = c1.y, x31_0 = c1.z, x31_1 = c1.w;
    const float Go0 = c2.x, Go1 = c2.y, ho = c2.z;
    const float C = c3.x, u = c3.y, w = c3.z, pp = c3.w;

    auto G0 = [&](float X, float Y) { return fmaf(Y, tvc, fmaf(-X, tvs, A0)); };
    auto G1 = [&](float X, float Y) { return fmaf(Y, ts,  fmaf( X, tc,  A1)); };
    auto H  = [&](float X, float Y, float Q) {
        return fmaf(pp, Q, fmaf(w, Y, fmaf(u, X, C)));
    };

    const unsigned base = (unsigned)row * 773u;
    float* a0p = out + (base - (unsigned)PH);        // 16B-aligned

    // chunk A: k = l+1
    f32x4 vA;
    if (PH == 0 || PH == 2)
        vA = (f32x4){G0(f.Ax[0],f.Ay[0]), G1(f.Ax[0],f.Ay[0]),
                     G0(f.Ax[1],f.Ay[1]), G1(f.Ax[1],f.Ay[1])};
    else
        vA = (f32x4){G1(f.Ax[0],f.Ay[0]), G0(f.Ax[1],f.Ay[1]),
                     G1(f.Ax[1],f.Ay[1]), G0(f.Ax[2],f.Ay[2])};
    if (PH == 3 && l == 0) vA.x = x31_1;             // f=1
    *(f32x4*)(a0p + 4 * (l + 1)) = vA;

    // chunk B: k = l+65
    f32x4 vB;
    if (PH == 0 || PH == 2)
        vB = (f32x4){G0(f.Bx[0],f.By[0]), G1(f.Bx[0],f.By[0]),
                     G0(f.Bx[1],f.By[1]), G1(f.Bx[1],f.By[1])};
    else
        vB = (f32x4){G1(f.Bx[0],f.By[0]), G0(f.Bx[1],f.By[1]),
                     G1(f.Bx[1],f.By[1]), G0(f.Bx[2],f.By[2])};
    if (l == 63) {                                   // i>=512 -> Go
        if (PH == 0) { vB.z = Go0; vB.w = Go1; }
        if (PH == 1) { vB.w = Go0; }
    }
    *(f32x4*)(a0p + 4 * (l + 65)) = vB;

    // chunk C: k = l+129
    f32x4 vC = (f32x4){H(f.Cx[0],f.Cy[0],f.Cq[0]), H(f.Cx[1],f.Cy[1],f.Cq[1]),
                       H(f.Cx[2],f.Cy[2],f.Cq[2]), H(f.Cx[3],f.Cy[3],f.Cq[3])};
    if (l == 0) {                                    // m<0 -> G511/Go
        if (PH == 1) { vC.x = Go1; }
        if (PH == 2) { vC.x = Go0; vC.y = Go1; }
        if (PH == 3) { vC.x = G1(f.e255x, f.e255y); vC.y = Go0; vC.z = Go1; }
    }
    *(f32x4*)(a0p + 4 * (l + 129)) = vC;

    // head chunk k=0 (lane 0)
    if (l == 0) {
        if (PH == 0) {
            *(f32x4*)a0p = (f32x4){x31_0, x31_1, G0(f.o0x,f.o0y), G1(f.o0x,f.o0y)};
        } else if (PH == 1) {
            a0p[1] = x31_0;
            *(f32x2*)(a0p + 2) = (f32x2){x31_1, G0(f.o0x,f.o0y)};
        } else if (PH == 2) {
            *(f32x2*)(a0p + 2) = (f32x2){x31_0, x31_1};
        } else {
            a0p[3] = x31_0;
        }
    }
    // tail chunk k=193 (lane 1)
    else if (l == 1) {
        float* tp = a0p + 772;                       // 16B-aligned
        if (PH == 0) {
            tp[0] = ho;
        } else if (PH == 1) {
            *(f32x2*)tp = (f32x2){H(f.Tx[2],f.Ty[2],f.Tq[2]), ho};
        } else if (PH == 2) {
            *(f32x2*)tp = (f32x2){H(f.Tx[1],f.Ty[1],f.Tq[1]),
                                  H(f.Tx[2],f.Ty[2],f.Tq[2])};
            tp[2] = ho;
        } else {
            *(f32x4*)tp = (f32x4){H(f.Tx[0],f.Ty[0],f.Tq[0]),
                                  H(f.Tx[1],f.Ty[1],f.Tq[1]),
                                  H(f.Tx[2],f.Ty[2],f.Tq[2]), ho};
        }
    }
}

__device__ __forceinline__ void load_x(const float* __restrict__ x, int row,
                                       float (&xr)[8])
{
    const float4 xa = *(const float4*)(x + (size_t)row * 8);
    const float4 xb = *(const float4*)(x + (size_t)row * 8 + 4);
    xr[0]=xa.x; xr[1]=xa.y; xr[2]=xa.z; xr[3]=xa.w;
    xr[4]=xb.x; xr[5]=xb.y; xr[6]=xb.z; xr[7]=xb.w;
}

template<int HALF>
__device__ __forceinline__ void A1_iter(
    const float (&xr)[8], float (&acc)[32], int it,
    const float* __restrict__ W1, const float* __restrict__ b1,
    const float* __restrict__ Wh)
{
    const int i0 = HALF * 64 + it * 8;
    float hh[8];
    #pragma unroll
    for (int u = 0; u < 8; ++u) {
        float a = b1[i0 + u];
        #pragma unroll
        for (int k = 0; k < 8; ++k)
            a = fmaf(xr[k], W1[k * 128 + i0 + u], a);
        hh[u] = fmaxf(a, 0.0f);
    }
    #pragma unroll
    for (int u = 0; u < 8; ++u) {
        #pragma unroll
        for (int k = 0; k < 32; ++k)
            acc[k] = fmaf(hh[u], Wh[(i0 + u) * 32 + k], acc[k]);
    }
}

template<int ROLE>
__device__ __forceinline__ void A2(
    int l, const float (&xr)[8], float (&acc)[32],
    const float (&pacc)[2][64][33],
    const float* __restrict__ input_mean, const float* __restrict__ input_std,
    const float* __restrict__ W31, const float* __restrict__ b31,
    const float* __restrict__ W32, const float* __restrict__ b32,
    float (&prmg)[64][16])
{
    #pragma unroll
    for (int k = 0; k < 32; ++k) acc[k] += pacc[ROLE][l][k];

    const float* Wo = ROLE ? W32 : W31;
    const float* bo = ROLE ? b32 : b31;
    float o0 = bo[0], o1 = bo[1];
    #pragma unroll
    for (int k = 0; k < 32; ++k) {
        float a = fmaxf(acc[k], 0.0f);
        o0 = fmaf(a, Wo[k * 2 + 0], o0);
        o1 = fmaf(a, Wo[k * 2 + 1], o1);
    }

    float x0v[8];
    #pragma unroll
    for (int k = 0; k < 8; ++k)
        x0v[k] = fmaf(xr[k], input_std[k], input_mean[k]);
    const float px = x0v[0], py = x0v[1], th = x0v[2], v = x0v[3];
    const float opx = x0v[4], opy = x0v[5], oth = x0v[6], ov = x0v[7];

    float st, ct, sto, cto;
    sincosf(th,  &st,  &ct);
    sincosf(oth, &sto, &cto);

    const float tvs = 2.0f * v * st;
    const float tvc = 2.0f * v * ct;
    const float tc  = 2.0f * ct;
    const float ts  = 2.0f * st;
    const float hc  = 2.0f * v * v;

    const float dxo = px - opx, dyo = py - opy;

    if (ROLE == 0) {
        const float A0  = px * tvs - py * tvc;
        const float A1  = -(px * tc + py * ts);
        const float Go0 = dxo * tvs - dyo * tvc;
        const float Go1 = -(dxo * tc + dyo * ts);
        *(f32x4*)&prmg[l][0] = (f32x4){A0, tvs, tvc, A1};
        *(f32x4*)&prmg[l][4] = (f32x4){tc, ts, o0, o1};
        *(f32x2*)&prmg[l][8] = (f32x2){Go0, Go1};
    } else {
        const float p0 = 4.0f / (1.0f + __expf(-o0));
        const float p1 = 4.0f / (1.0f + __expf(-o1));
        const float ps = p0 + p1;
        const float pp = p0 * p1;
        const float B0 = px * tvc + py * tvs;
        const float C  = hc + ps * B0 + pp * (px * px + py * py);
        const float u  = -(ps * tvc) - 2.0f * pp * px;
        const float w  = -(ps * tvs) - 2.0f * pp * py;
        const float ob  = dxo * dxo + dyo * dyo - 1.21f;     // Ro^2
        const float rvx = v * ct - ov * cto;
        const float rvy = v * st - ov * sto;
        const float obd = 2.0f * (dxo * rvx + dyo * rvy);
        const float cth_sum = ct * cto - st * sto;            // cos(th+oth)
        const float oLf2b = 2.0f * (v * v + ov * ov - 2.0f * v * ov * cth_sum);
        const float ho = oLf2b + ps * obd + pp * ob;
        *(f32x2*)&prmg[l][10]  = (f32x2){ho, 0.0f};
        *(f32x4*)&prmg[l][12]  = (f32x4){C, u, w, pp};
    }
}

template<int PH>
__device__ __forceinline__ void flow(
    int blockRow0, int l,
    float (&pacc)[2][64][33], float (&prm)[64][16],
    const float* __restrict__ x,
    const float* __restrict__ obstacles,
    const float* __restrict__ input_mean, const float* __restrict__ input_std,
    const float* __restrict__ W1,  const float* __restrict__ b1,
    const float* __restrict__ W21, const float* __restrict__ b21,
    const float* __restrict__ W22, const float* __restrict__ b22,
    const float* __restrict__ W31, const float* __restrict__ b31,
    const float* __restrict__ W32, const float* __restrict__ b32,
    float* __restrict__ out)
{
    constexpr int ROLE = PH & 1;
    constexpr int HALF = PH >> 1;
    const float* Wh = ROLE ? W22 : W21;
    const float* bh = ROLE ? b22 : b21;

    // (a) feats issued FIRST — VMEM latency hides under A's VALU
    Feats f;
    load_feats<PH>(l, obstacles, f);

    // ---- phase A (R10-identical) -------------------------------------------
    float xr[8];
    load_x(x, blockRow0 + l, xr);
    float acc[32];
    #pragma unroll
    for (int k = 0; k < 32; ++k) acc[k] = HALF ? 0.0f : bh[k];
    #pragma unroll 1
    for (int it = 0; it < 8; ++it)
        A1_iter<HALF>(xr, acc, it, W1, b1, Wh);
    if (HALF == 0) {
        #pragma unroll
        for (int k = 0; k < 32; ++k) pacc[ROLE][l][k] = acc[k];
    }
    __syncthreads();                                 // pacc ready
    if (HALF == 1)
        A2<ROLE>(l, xr, acc, pacc, input_mean, input_std,
                 W31, b31, W32, b32, prm);
    __syncthreads();                                 // prm ready

    // ---- phase B: depth-2 prm prefetch pipeline ----------------------------
    f32x4 p0 = *(const f32x4*)&prm[PH][0];
    f32x4 p1 = *(const f32x4*)&prm[PH][4];
    f32x4 p2 = *(const f32x4*)&prm[PH][8];
    f32x4 p3 = *(const f32x4*)&prm[PH][12];
    #pragma unroll 1
    for (int t = 0; t < 16; ++t) {
        const f32x4 c0 = p0, c1 = p1, c2 = p2, c3 = p3;
        if (t < 15) {
            const int rn = 4 * (t + 1) + PH;
            p0 = *(const f32x4*)&prm[rn][0];
            p1 = *(const f32x4*)&prm[rn][4];
            p2 = *(const f32x4*)&prm[rn][8];
            p3 = *(const f32x4*)&prm[rn][12];
        }
        b_row<PH>(blockRow0 + 4 * t + PH, l, c0, c1, c2, c3, f, out);
    }
}

__global__ __launch_bounds__(256, 4) void fused7(
    const float* __restrict__ x,
    const float* __restrict__ obstacles,
    const float* __restrict__ input_mean, const float* __restrict__ input_std,
    const float* __restrict__ W1,  const float* __restrict__ b1,
    const float* __restrict__ W21, const float* __restrict__ b21,
    const float* __restrict__ W22, const float* __restrict__ b22,
    const float* __restrict__ W31, const float* __restrict__ b31,
    const float* __restrict__ W32, const float* __restrict__ b32,
    float* __restrict__ out)
{
    __shared__ float pacc[2][64][33];   // partial acc exchange (+1 pad)
    __shared__ float prm[64][16];       // per-row coefficients

    const int tid = threadIdx.x;
    const int l   = tid & 63;
    const int wv  = __builtin_amdgcn_readfirstlane(tid >> 6);   // 0..3
    const int blockRow0 = blockIdx.x * 64;

    if      (wv == 0) flow<0>(blockRow0, l, pacc, prm, x, obstacles,
                              input_mean, input_std, W1, b1, W21, b21,
                              W22, b22, W31, b31, W32, b32, out);
    else if (wv == 1) flow<1>(blockRow0, l, pacc, prm, x, obstacles,
                              input_mean, input_std, W1, b1, W21, b21,
                              W22, b22, W31, b31, W32, b32, out);
    else if (wv == 2) flow<2>(blockRow0, l, pacc, prm, x, obstacles,
                              input_mean, input_std, W1, b1, W21, b21,
                              W22, b22, W31, b31, W32, b32, out);
    else              flow<3>(blockRow0, l, pacc, prm, x, obstacles,
                              input_mean, input_std, W1, b1, W21, b21,
                              W22, b22, W31, b31, W32, b32, out);
}

extern "C" void kernel_launch(void* const* d_in, const int* in_sizes, int n_in,
                              void* d_out, int out_size, void* d_ws, size_t ws_size,
                              hipStream_t stream) {
    const float* x          = (const float*)d_in[0];
    const float* obstacles  = (const float*)d_in[1];
    const float* input_mean = (const float*)d_in[2];
    const float* input_std  = (const float*)d_in[3];
    const float* W1  = (const float*)d_in[4];
    const float* b1  = (const float*)d_in[5];
    const float* W21 = (const float*)d_in[6];
    const float* b21 = (const float*)d_in[7];
    const float* W22 = (const float*)d_in[8];
    const float* b22 = (const float*)d_in[9];
    const float* W31 = (const float*)d_in[10];
    const float* b31 = (const float*)d_in[11];
    const float* W32 = (const float*)d_in[12];
    const float* b32 = (const float*)d_in[13];

    float* out = (float*)d_out;

    // 1024 blocks x 256 threads, 64 rows/block — R10's proven shape.
    fused7<<<dim3(NB_TOTAL / 64), dim3(256), 0, stream>>>(
        x, obstacles, input_mean, input_std,
        W1, b1, W21, b21, W22, b22, W31, b31, W32, b32, out);
}

// Round 14
// 50.662 us; speedup vs baseline: 1.2113x; 1.0471x over previous
//
#include <hip/hip_runtime.h>
#include <math.h>

#define NB_TOTAL 65536
#define OUTS 773            // 2 + 514 + 257

typedef float f32x4 __attribute__((ext_vector_type(4)));
typedef float f32x2 __attribute__((ext_vector_type(2)));

// Output row layout (f32):
//  [0..1] x31 | [2+i] G flat i=2j+comp (512 vals) | [514,515] G_o
//  [516+m] h_s | [772] h_o
//
// prm row layout (16 f32):
//  [0]A0 [1]tvs [2]tvc [3]A1 | [4]tc [5]ts [6]x31_0 [7]x31_1
//  [8]Go0 [9]Go1 [10]ho [11]- | [12]C [13]u [14]w [15]pp
//  G0(j) = A0 - tvs*ox + tvc*oy ; G1(j) = A1 + tc*ox + ts*oy
//  h(m)  = C + u*ox + w*oy + pp*q ; q = ox^2+oy^2-R^2
//
// R14 = R10's kernel BYTE-IDENTICAL except __launch_bounds__(256,2):
//  1024 blocks, 2 resident/CU -> 2 generations. Gen-2 blocks' phase-A VALU
//  hides under gen-1 blocks' phase-B store drain (hardware-scheduled block
//  stagger — no in-wave interleave, which failed in R11/R12).
//  Fill-kernel evidence: 6.9 TB/s at ~3 waves/CU -> 8 waves/CU sustains drain.
// R7 lesson: only 16B-ALIGNED dwordx4 stores. R9 lesson: one row's chunk
// values in flight. R13 lesson: prm ds_read latency & feats placement are nulls.

__device__ __forceinline__ int iclamp(int v, int lo, int hi) {
    return v < lo ? lo : (v > hi ? hi : v);
}

template<int PH>
__device__ __forceinline__ void phase_rows(
    int blockRow0, int l,
    const float (&prm)[64][16],
    const float* __restrict__ obstacles,
    float* __restrict__ out)
{
    // ---- per-phase obstacle features (registers) --------------------------
    constexpr int aStart = (PH == 0) ? 1 : (PH == 3 ? -1 : 0);
    constexpr int nA = (PH == 0 || PH == 2) ? 2 : 3;

    float Ax[3], Ay[3];
    #pragma unroll
    for (int c = 0; c < nA; ++c) {
        const int j = iclamp(2 * l + aStart + c, 0, 255);
        const float* o = obstacles + (size_t)j * 3;
        Ax[c] = o[0]; Ay[c] = o[1];
    }
    float Bx[3], By[3];
    #pragma unroll
    for (int c = 0; c < nA; ++c) {
        const int j = iclamp(2 * l + 128 + aStart + c, 0, 255);
        const float* o = obstacles + (size_t)j * 3;
        Bx[c] = o[0]; By[c] = o[1];
    }
    float Cx[4], Cy[4], Cq[4];
    #pragma unroll
    for (int c = 0; c < 4; ++c) {
        const int j = iclamp(4 * l - PH + c, 0, 255);
        const float* o = obstacles + (size_t)j * 3;
        const float a = o[0], b = o[1], r = o[2] + 0.6f;  // R = 0.5+rad+0.1
        Cx[c] = a; Cy[c] = b; Cq[c] = fmaf(a, a, b * b) - r * r;
    }
    float o0x = 0.f, o0y = 0.f, e255x = 0.f, e255y = 0.f;
    if (PH == 0 || PH == 1) { o0x = obstacles[0]; o0y = obstacles[1]; }
    if (PH == 3) { e255x = obstacles[255 * 3]; e255y = obstacles[255 * 3 + 1]; }
    float Tx[3], Ty[3], Tq[3];          // h[253..255] features (tail, lane 1)
    if (PH >= 1) {
        #pragma unroll
        for (int c = 0; c < 3; ++c) {
            const float* o = obstacles + (size_t)(253 + c) * 3;
            const float a = o[0], b = o[1], r = o[2] + 0.6f;
            Tx[c] = a; Ty[c] = b; Tq[c] = fmaf(a, a, b * b) - r * r;
        }
    }

    // ---- 16 rows, one per iteration (keep live-set to ONE row) ------------
    #pragma unroll 1
    for (int t = 0; t < 16; ++t) {
        const int rloc = 4 * t + PH;
        const int row  = blockRow0 + rloc;

        const f32x4 c0 = *(const f32x4*)&prm[rloc][0];
        const f32x4 c1 = *(const f32x4*)&prm[rloc][4];
        const f32x4 c2 = *(const f32x4*)&prm[rloc][8];
        const f32x4 c3 = *(const f32x4*)&prm[rloc][12];
        const float A0 = c0.x, tvs = c0.y, tvc = c0.z, A1 = c0.w;
        const float tc = c1.x, ts  = c1.y, x31_0 = c1.z, x31_1 = c1.w;
        const float Go0 = c2.x, Go1 = c2.y, ho = c2.z;
        const float C = c3.x, u = c3.y, w = c3.z, pp = c3.w;

        auto G0 = [&](float X, float Y) { return fmaf(Y, tvc, fmaf(-X, tvs, A0)); };
        auto G1 = [&](float X, float Y) { return fmaf(Y, ts,  fmaf( X, tc,  A1)); };
        auto H  = [&](float X, float Y, float Q) {
            return fmaf(pp, Q, fmaf(w, Y, fmaf(u, X, C)));
        };

        const unsigned base = (unsigned)row * 773u;
        float* a0p = out + (base - (unsigned)PH);        // 16B-aligned

        // chunk A: k = l+1
        f32x4 vA;
        if (PH == 0 || PH == 2)
            vA = (f32x4){G0(Ax[0],Ay[0]), G1(Ax[0],Ay[0]),
                         G0(Ax[1],Ay[1]), G1(Ax[1],Ay[1])};
        else
            vA = (f32x4){G1(Ax[0],Ay[0]), G0(Ax[1],Ay[1]),
                         G1(Ax[1],Ay[1]), G0(Ax[2],Ay[2])};
        if (PH == 3 && l == 0) vA.x = x31_1;             // f=1
        *(f32x4*)(a0p + 4 * (l + 1)) = vA;

        // chunk B: k = l+65
        f32x4 vB;
        if (PH == 0 || PH == 2)
            vB = (f32x4){G0(Bx[0],By[0]), G1(Bx[0],By[0]),
                         G0(Bx[1],By[1]), G1(Bx[1],By[1])};
        else
            vB = (f32x4){G1(Bx[0],By[0]), G0(Bx[1],By[1]),
                         G1(Bx[1],By[1]), G0(Bx[2],By[2])};
        if (l == 63) {                                   // i>=512 -> Go
            if (PH == 0) { vB.z = Go0; vB.w = Go1; }
            if (PH == 1) { vB.w = Go0; }
        }
        *(f32x4*)(a0p + 4 * (l + 65)) = vB;

        // chunk C: k = l+129
        f32x4 vC = (f32x4){H(Cx[0],Cy[0],Cq[0]), H(Cx[1],Cy[1],Cq[1]),
                           H(Cx[2],Cy[2],Cq[2]), H(Cx[3],Cy[3],Cq[3])};
        if (l == 0) {                                    // m<0 -> G511/Go
            if (PH == 1) { vC.x = Go1; }
            if (PH == 2) { vC.x = Go0; vC.y = Go1; }
            if (PH == 3) { vC.x = G1(e255x, e255y); vC.y = Go0; vC.z = Go1; }
        }
        *(f32x4*)(a0p + 4 * (l + 129)) = vC;

        // head chunk k=0 (lane 0): f = t-PH
        if (l == 0) {
            if (PH == 0) {
                *(f32x4*)a0p = (f32x4){x31_0, x31_1, G0(o0x,o0y), G1(o0x,o0y)};
            } else if (PH == 1) {
                a0p[1] = x31_0;
                *(f32x2*)(a0p + 2) = (f32x2){x31_1, G0(o0x,o0y)};
            } else if (PH == 2) {
                *(f32x2*)(a0p + 2) = (f32x2){x31_0, x31_1};
            } else {
                a0p[3] = x31_0;
            }
        }
        // tail chunk k=193 (lane 1): f = 772-PH+t
        else if (l == 1) {
            float* tp = a0p + 772;                       // 16B-aligned
            if (PH == 0) {
                tp[0] = ho;
            } else if (PH == 1) {
                *(f32x2*)tp = (f32x2){H(Tx[2],Ty[2],Tq[2]), ho};
            } else if (PH == 2) {
                *(f32x2*)tp = (f32x2){H(Tx[1],Ty[1],Tq[1]), H(Tx[2],Ty[2],Tq[2])};
                tp[2] = ho;
            } else {
                *(f32x4*)tp = (f32x4){H(Tx[0],Ty[0],Tq[0]), H(Tx[1],Ty[1],Tq[1]),
                                      H(Tx[2],Ty[2],Tq[2]), ho};
            }
        }
    }
}

__global__ __launch_bounds__(256, 2) void fused8(
    const float* __restrict__ x,
    const float* __restrict__ obstacles,
    const float* __restrict__ input_mean, const float* __restrict__ input_std,
    const float* __restrict__ W1,  const float* __restrict__ b1,
    const float* __restrict__ W21, const float* __restrict__ b21,
    const float* __restrict__ W22, const float* __restrict__ b22,
    const float* __restrict__ W31, const float* __restrict__ b31,
    const float* __restrict__ W32, const float* __restrict__ b32,
    float* __restrict__ out)
{
    __shared__ float pacc[2][64][33];   // partial acc exchange (+1 pad)
    __shared__ float prm[64][16];       // per-row coefficients

    const int tid  = threadIdx.x;
    const int l    = tid & 63;
    const int wv   = __builtin_amdgcn_readfirstlane(tid >> 6);
    const int role = wv & 1;
    const int half = wv >> 1;
    const int row  = blockIdx.x * 64 + l;

    // ======================= Phase A: MLP + coefficients (R10, proven) =====
    float xr[8];
    {
        const float4 xa = *(const float4*)(x + (size_t)row * 8);
        const float4 xb = *(const float4*)(x + (size_t)row * 8 + 4);
        xr[0]=xa.x; xr[1]=xa.y; xr[2]=xa.z; xr[3]=xa.w;
        xr[4]=xb.x; xr[5]=xb.y; xr[6]=xb.z; xr[7]=xb.w;
    }

    const float* Wh = role ? W22 : W21;
    const float* bh = role ? b22 : b21;

    float acc[32];
    #pragma unroll
    for (int k = 0; k < 32; ++k) acc[k] = half ? 0.0f : bh[k];

    const int ibeg = half * 64;
    #pragma unroll 1
    for (int i0 = ibeg; i0 < ibeg + 64; i0 += 8) {
        float hh[8];
        #pragma unroll
        for (int u = 0; u < 8; ++u) {
            float a = b1[i0 + u];
            #pragma unroll
            for (int k = 0; k < 8; ++k)
                a = fmaf(xr[k], W1[k * 128 + i0 + u], a);
            hh[u] = fmaxf(a, 0.0f);
        }
        #pragma unroll
        for (int u = 0; u < 8; ++u) {
            #pragma unroll
            for (int k = 0; k < 32; ++k)
                acc[k] = fmaf(hh[u], Wh[(i0 + u) * 32 + k], acc[k]);
        }
    }

    if (half == 0) {
        #pragma unroll
        for (int k = 0; k < 32; ++k) pacc[role][l][k] = acc[k];
    }
    __syncthreads();

    if (half == 1) {
        #pragma unroll
        for (int k = 0; k < 32; ++k) acc[k] += pacc[role][l][k];

        const float* Wo = role ? W32 : W31;
        const float* bo = role ? b32 : b31;
        float o0 = bo[0], o1 = bo[1];
        #pragma unroll
        for (int k = 0; k < 32; ++k) {
            float a = fmaxf(acc[k], 0.0f);
            o0 = fmaf(a, Wo[k * 2 + 0], o0);
            o1 = fmaf(a, Wo[k * 2 + 1], o1);
        }

        float x0v[8];
        #pragma unroll
        for (int k = 0; k < 8; ++k)
            x0v[k] = fmaf(xr[k], input_std[k], input_mean[k]);
        const float px = x0v[0], py = x0v[1], th = x0v[2], v = x0v[3];
        const float opx = x0v[4], opy = x0v[5], oth = x0v[6], ov = x0v[7];

        float st, ct, sto, cto;
        sincosf(th,  &st,  &ct);
        sincosf(oth, &sto, &cto);

        const float tvs = 2.0f * v * st;
        const float tvc = 2.0f * v * ct;
        const float tc  = 2.0f * ct;
        const float ts  = 2.0f * st;
        const float hc  = 2.0f * v * v;

        const float dxo = px - opx, dyo = py - opy;

        if (role == 0) {
            const float A0  = px * tvs - py * tvc;
            const float A1  = -(px * tc + py * ts);
            const float Go0 = dxo * tvs - dyo * tvc;
            const float Go1 = -(dxo * tc + dyo * ts);
            *(f32x4*)&prm[l][0] = (f32x4){A0, tvs, tvc, A1};
            *(f32x4*)&prm[l][4] = (f32x4){tc, ts, o0, o1};
            *(f32x2*)&prm[l][8] = (f32x2){Go0, Go1};
        } else {
            const float p0 = 4.0f / (1.0f + __expf(-o0));
            const float p1 = 4.0f / (1.0f + __expf(-o1));
            const float ps = p0 + p1;
            const float pp = p0 * p1;
            const float B0 = px * tvc + py * tvs;
            const float C  = hc + ps * B0 + pp * (px * px + py * py);
            const float u  = -(ps * tvc) - 2.0f * pp * px;
            const float w  = -(ps * tvs) - 2.0f * pp * py;
            const float ob  = dxo * dxo + dyo * dyo - 1.21f;     // Ro^2
            const float rvx = v * ct - ov * cto;
            const float rvy = v * st - ov * sto;
            const float obd = 2.0f * (dxo * rvx + dyo * rvy);
            const float cth_sum = ct * cto - st * sto;            // cos(th+oth)
            const float oLf2b = 2.0f * (v * v + ov * ov - 2.0f * v * ov * cth_sum);
            const float ho = oLf2b + ps * obd + pp * ob;
            *(f32x2*)&prm[l][10]  = (f32x2){ho, 0.0f};
            *(f32x4*)&prm[l][12]  = (f32x4){C, u, w, pp};
        }
    }
    __syncthreads();

    // ======================= Phase B: one phase per wave ====================
    const int blockRow0 = blockIdx.x * 64;
    if      (wv == 0) phase_rows<0>(blockRow0, l, prm, obstacles, out);
    else if (wv == 1) phase_rows<1>(blockRow0, l, prm, obstacles, out);
    else if (wv == 2) phase_rows<2>(blockRow0, l, prm, obstacles, out);
    else              phase_rows<3>(blockRow0, l, prm, obstacles, out);
}

extern "C" void kernel_launch(void* const* d_in, const int* in_sizes, int n_in,
                              void* d_out, int out_size, void* d_ws, size_t ws_size,
                              hipStream_t stream) {
    const float* x          = (const float*)d_in[0];
    const float* obstacles  = (const float*)d_in[1];
    const float* input_mean = (const float*)d_in[2];
    const float* input_std  = (const float*)d_in[3];
    const float* W1  = (const float*)d_in[4];
    const float* b1  = (const float*)d_in[5];
    const float* W21 = (const float*)d_in[6];
    const float* b21 = (const float*)d_in[7];
    const float* W22 = (const float*)d_in[8];
    const float* b22 = (const float*)d_in[9];
    const float* W31 = (const float*)d_in[10];
    const float* b31 = (const float*)d_in[11];
    const float* W32 = (const float*)d_in[12];
    const float* b32 = (const float*)d_in[13];

    float* out = (float*)d_out;

    // 1024 blocks x 256 threads, 64 rows/block; 2 resident/CU -> stagger.
    fused8<<<dim3(NB_TOTAL / 64), dim3(256), 0, stream>>>(
        x, obstacles, input_mean, input_std,
        W1, b1, W21, b21, W22, b22, W31, b31, W32, b32, out);
}